// Round 6
// baseline (4615.221 us; speedup 1.0000x reference)
//
#include <hip/hip_runtime.h>
#include <hip/hip_bf16.h>
#include <stdint.h>

// Fused 2-layer ReLU RNN, B=64 T=2048 D=H=256 O=128.  Correctness-first rewrite:
// NO inline asm, NO ds_read_b64_tr_b16, NO v_cvt_pk — pure HIP + MFMA intrinsics.
// Only HW-layout assumptions: C/D col=lane&15,row=4*(lane>>4)+reg [verified] and
// dual row-major A/B fragments (row=lane&15, k=8*(lane>>4)+j up to a shared
// bijection, which cancels between A and B).
//
// Phases: proj0 -> recur0 (writes h1 as fragment-slot images) -> proj1 -> recur1+FC.
// h LDS layout (A-slot-linear): byte(m,k) = (k>>5)*1024 + ((k>>3)&3)*256 + m*16 + (k&7)*2
//   => reader lane L, k-block c does ONE ds_read_b128 at c*1024 + L*16 (conflict-free);
//   => writer scatters 16 ds_write_b16 per lane from the (verified) C/D fragment.
// Workspace tiers: ws >= 192MiB: fp32 xp (128M) + h1 slots (64M); else bf16 xp (64M) + h1 (64M).

typedef float    f32x4  __attribute__((ext_vector_type(4)));
typedef short    s16x8  __attribute__((ext_vector_type(8)));
typedef uint32_t u32x2  __attribute__((ext_vector_type(2)));
typedef uint32_t u32x4v __attribute__((ext_vector_type(4)));

#define T_STEPS 2048

template<bool C, class A, class B> struct cond_ { using type = A; };
template<class A, class B> struct cond_<false, A, B> { using type = B; };

static __device__ __forceinline__ ushort f2bf(float f) {  // RNE f32->bf16 (finite inputs)
  uint32_t u = __builtin_bit_cast(uint32_t, f);
  u += 0x7fffu + ((u >> 16) & 1u);
  return (ushort)(u >> 16);
}
static __device__ __forceinline__ float bf2f(ushort h) {
  return __builtin_bit_cast(float, (uint32_t)h << 16);
}
static __device__ __forceinline__ uint32_t packbf(float lo, float hi) {
  return (uint32_t)f2bf(lo) | ((uint32_t)f2bf(hi) << 16);
}
static __device__ __forceinline__ s16x8 pack8(float4 a, float4 b) {
  u32x4v u;
  u.x = packbf(a.x, a.y); u.y = packbf(a.z, a.w);
  u.z = packbf(b.x, b.y); u.w = packbf(b.z, b.w);
  return __builtin_bit_cast(s16x8, u);
}
struct hl2 { uint32_t hi, lo; };
static __device__ __forceinline__ hl2 split2(float a, float b) {  // hi/lo bf16 pair-pack
  const ushort ha = f2bf(a), hb = f2bf(b);
  const ushort la = f2bf(a - bf2f(ha)), lb = f2bf(b - bf2f(hb));
  hl2 r;
  r.hi = (uint32_t)ha | ((uint32_t)hb << 16);
  r.lo = (uint32_t)la | ((uint32_t)lb << 16);
  return r;
}
static __device__ __forceinline__ f32x4 expand16(u32x2 p) {  // 4 bf16 -> f32x4 (exact)
  f32x4 r;
  r.x = __builtin_bit_cast(float, p.x << 16);
  r.y = __builtin_bit_cast(float, p.x & 0xffff0000u);
  r.z = __builtin_bit_cast(float, p.y << 16);
  r.w = __builtin_bit_cast(float, p.y & 0xffff0000u);
  return r;
}
static __device__ __forceinline__ f32x4 acc_of(f32x4 v) { return v; }
static __device__ __forceinline__ f32x4 acc_of(u32x2 v) { return expand16(v); }

#define MFMA16(a, b, c) __builtin_amdgcn_mfma_f32_16x16x32_bf16((a), (b), (c), 0, 0, 0)

// ---------------- Projection GEMM:  xp[t][b][:] = in_row . W^T + (ba+bb) ----------------
// grid 256 x 256 threads. Wave w owns N-tiles 4w..4w+3.
// MODE 0: inp = fp32 x [B][T][D].  MODE 1: inp = h1 fragment-slot bytes (from recur0).
// Output fragment-linear: frag idx = ((t*4+bg)*16 + nt)*64 + lane (f32x4 or u32x2 per tier).
template<int MODE, bool XP16>
__global__ __launch_bounds__(256, 2)
void proj_kernel(const void* __restrict__ inp, const float* __restrict__ W,
                 const float* __restrict__ ba, const float* __restrict__ bb,
                 void* __restrict__ xp)
{
  const int tid = threadIdx.x;
  const int w = tid >> 6, lane = tid & 63, q = lane >> 4, r = lane & 15;

  s16x8 wf[4][8];
  float bs[4];
#pragma unroll
  for (int n = 0; n < 4; ++n) {
    const int j = 16 * (4 * w + n) + r;
    bs[n] = ba[j] + bb[j];
    const float* wr = W + (size_t)j * 256 + 8 * q;
#pragma unroll
    for (int c = 0; c < 8; ++c) {
      const float4 f0 = *(const float4*)(wr + 32 * c);
      const float4 f1 = *(const float4*)(wr + 32 * c + 4);
      wf[n][c] = pack8(f0, f1);
    }
  }

  const int t0 = blockIdx.x * 8;
  for (int tt = 0; tt < 8; ++tt) {
    const int t = t0 + tt;
    for (int bg = 0; bg < 4; ++bg) {
      s16x8 af[8];
      if (MODE == 1) {
        const unsigned char* hsl = (const unsigned char*)inp
            + (size_t)t * 32768 + (size_t)bg * 8192 + lane * 16;
#pragma unroll
        for (int c = 0; c < 8; ++c)
          af[c] = __builtin_bit_cast(s16x8, *(const u32x4v*)(hsl + c * 1024));
      } else {
        const float* arow = (const float*)inp + ((size_t)(16 * bg + r) * 2048 + t) * 256 + 8 * q;
#pragma unroll
        for (int c = 0; c < 8; ++c) {
          const float4 f0 = *(const float4*)(arow + 32 * c);
          const float4 f1 = *(const float4*)(arow + 32 * c + 4);
          af[c] = pack8(f0, f1);
        }
      }
      f32x4 a0 = {bs[0], bs[0], bs[0], bs[0]};
      f32x4 a1 = {bs[1], bs[1], bs[1], bs[1]};
      f32x4 a2 = {bs[2], bs[2], bs[2], bs[2]};
      f32x4 a3 = {bs[3], bs[3], bs[3], bs[3]};
#pragma unroll
      for (int c = 0; c < 8; ++c) {
        a0 = MFMA16(af[c], wf[0][c], a0);
        a1 = MFMA16(af[c], wf[1][c], a1);
        a2 = MFMA16(af[c], wf[2][c], a2);
        a3 = MFMA16(af[c], wf[3][c], a3);
      }
      const int ob = (t * 4 + bg) * 1024 + (4 * w) * 64 + lane;
      if constexpr (XP16) {
        u32x2* const xpo = (u32x2*)xp;
        u32x2 s0, s1, s2, s3;
        s0.x = packbf(a0.x, a0.y); s0.y = packbf(a0.z, a0.w);
        s1.x = packbf(a1.x, a1.y); s1.y = packbf(a1.z, a1.w);
        s2.x = packbf(a2.x, a2.y); s2.y = packbf(a2.z, a2.w);
        s3.x = packbf(a3.x, a3.y); s3.y = packbf(a3.z, a3.w);
        xpo[ob +   0] = s0;
        xpo[ob +  64] = s1;
        xpo[ob + 128] = s2;
        xpo[ob + 192] = s3;
      } else {
        f32x4* const xpo = (f32x4*)xp;
        xpo[ob +   0] = a0;
        xpo[ob +  64] = a1;
        xpo[ob + 128] = a2;
        xpo[ob + 192] = a3;
      }
    }
  }
}

// ---------------- Persistent recurrence ----------------
// 4 WGs (bg = blockIdx), 4 waves, 16 batches/WG. h_t = relu(xp_t + W_hh h_{t-1}).
// W_hh (hi+lo bf16) loaded straight from global into VGPRs (no LDS staging).
// LDS: two 8KB h buffers in A-slot-linear layout (see header).
template<int LAYER, bool XP16>
__global__ __launch_bounds__(256, 1)
void recur_kernel(const void* __restrict__ xp, const float* __restrict__ Whh,
                  char* __restrict__ h1out, const float* __restrict__ fcw,
                  const float* __restrict__ fcb, float* __restrict__ out)
{
  using XPT = typename cond_<XP16, u32x2, f32x4>::type;
  const int tid = threadIdx.x;
  const int w = tid >> 6, lane = tid & 63, q = lane >> 4, r = lane & 15;
  const int bg = blockIdx.x;

  __shared__ __align__(16) unsigned char smem[16384];

  // ---- W_hh hi/lo direct load: lane (q,r), tile n holds W[16*(4w+n)+r][8q+32c+{0..7}] ----
  s16x8 whi[4][8], wlo[4][8];
#pragma unroll
  for (int n = 0; n < 4; ++n) {
    const float* wr = Whh + (size_t)(16 * (4 * w + n) + r) * 256 + 8 * q;
#pragma unroll
    for (int c = 0; c < 8; ++c) {
      const float4 f0 = *(const float4*)(wr + 32 * c);
      const float4 f1 = *(const float4*)(wr + 32 * c + 4);
      const hl2 p0 = split2(f0.x, f0.y);
      const hl2 p1 = split2(f0.z, f0.w);
      const hl2 p2 = split2(f1.x, f1.y);
      const hl2 p3 = split2(f1.z, f1.w);
      u32x4v H, L;
      H.x = p0.hi; L.x = p0.lo;
      H.y = p1.hi; L.y = p1.lo;
      H.z = p2.hi; L.z = p2.lo;
      H.w = p3.hi; L.w = p3.lo;
      whi[n][c] = __builtin_bit_cast(s16x8, H);
      wlo[n][c] = __builtin_bit_cast(s16x8, L);
    }
  }

  // ---- zero both h buffers ----
  {
    uint32_t* z = (uint32_t*)smem;
#pragma unroll
    for (int i = 0; i < 16; ++i) z[tid + 256 * i] = 0u;
  }
  __syncthreads();

  const XPT* __restrict__ xpv = (const XPT*)xp;
  const int xpbase = bg * 1024 + (4 * w) * 64 + lane;

  XPT pfA[4], pfB[4];
#pragma unroll
  for (int n = 0; n < 4; ++n) {
    pfA[n] = xpv[xpbase + n * 64];
    pfB[n] = xpv[4096 + xpbase + n * 64];
  }

  // write bases: value (tile n, reg j): m = 4q+j, k = 64w+16n+r
  int rb[4];
#pragma unroll
  for (int n = 0; n < 4; ++n) {
    const int k0 = 64 * w + 16 * n + r;
    rb[n] = (k0 >> 5) * 1024 + ((k0 >> 3) & 3) * 256 + (4 * q) * 16 + (k0 & 7) * 2;
  }
  const int rdoff = lane * 16;

#define RSTEP(T_, RD_, WR_, PF_) do {                                           \
    u32x4v afr[8];                                                              \
    _Pragma("unroll")                                                           \
    for (int c = 0; c < 8; ++c)                                                 \
      afr[c] = *(const u32x4v*)(smem + (RD_) + c * 1024 + rdoff);               \
    if (LAYER == 0 && w == 0 && (T_) > 0) {                                     \
      char* hb = h1out + (size_t)((T_) - 1) * 32768 + (size_t)bg * 8192 + rdoff;\
      _Pragma("unroll")                                                         \
      for (int c = 0; c < 8; ++c) *(u32x4v*)(hb + c * 1024) = afr[c];           \
    }                                                                           \
    f32x4 ac0 = acc_of(PF_[0]), ac1 = acc_of(PF_[1]);                           \
    f32x4 ac2 = acc_of(PF_[2]), ac3 = acc_of(PF_[3]);                           \
    { int tp = (T_) + 2; if (tp > T_STEPS - 1) tp = T_STEPS - 1;                \
      const int xo = tp * 4096 + xpbase;                                        \
      PF_[0] = xpv[xo]; PF_[1] = xpv[xo + 64];                                  \
      PF_[2] = xpv[xo + 128]; PF_[3] = xpv[xo + 192]; }                         \
    _Pragma("unroll")                                                           \
    for (int c = 0; c < 8; ++c) {                                               \
      const s16x8 a = __builtin_bit_cast(s16x8, afr[c]);                        \
      ac0 = MFMA16(a, whi[0][c], ac0); ac1 = MFMA16(a, whi[1][c], ac1);         \
      ac2 = MFMA16(a, whi[2][c], ac2); ac3 = MFMA16(a, whi[3][c], ac3);         \
      ac0 = MFMA16(a, wlo[0][c], ac0); ac1 = MFMA16(a, wlo[1][c], ac1);         \
      ac2 = MFMA16(a, wlo[2][c], ac2); ac3 = MFMA16(a, wlo[3][c], ac3);         \
    }                                                                           \
    unsigned char* const wb = smem + (WR_);                                     \
    *(ushort*)(wb + rb[0] +  0) = f2bf(fmaxf(ac0.x, 0.f));                      \
    *(ushort*)(wb + rb[0] + 16) = f2bf(fmaxf(ac0.y, 0.f));                      \
    *(ushort*)(wb + rb[0] + 32) = f2bf(fmaxf(ac0.z, 0.f));                      \
    *(ushort*)(wb + rb[0] + 48) = f2bf(fmaxf(ac0.w, 0.f));                      \
    *(ushort*)(wb + rb[1] +  0) = f2bf(fmaxf(ac1.x, 0.f));                      \
    *(ushort*)(wb + rb[1] + 16) = f2bf(fmaxf(ac1.y, 0.f));                      \
    *(ushort*)(wb + rb[1] + 32) = f2bf(fmaxf(ac1.z, 0.f));                      \
    *(ushort*)(wb + rb[1] + 48) = f2bf(fmaxf(ac1.w, 0.f));                      \
    *(ushort*)(wb + rb[2] +  0) = f2bf(fmaxf(ac2.x, 0.f));                      \
    *(ushort*)(wb + rb[2] + 16) = f2bf(fmaxf(ac2.y, 0.f));                      \
    *(ushort*)(wb + rb[2] + 32) = f2bf(fmaxf(ac2.z, 0.f));                      \
    *(ushort*)(wb + rb[2] + 48) = f2bf(fmaxf(ac2.w, 0.f));                      \
    *(ushort*)(wb + rb[3] +  0) = f2bf(fmaxf(ac3.x, 0.f));                      \
    *(ushort*)(wb + rb[3] + 16) = f2bf(fmaxf(ac3.y, 0.f));                      \
    *(ushort*)(wb + rb[3] + 32) = f2bf(fmaxf(ac3.z, 0.f));                      \
    *(ushort*)(wb + rb[3] + 48) = f2bf(fmaxf(ac3.w, 0.f));                      \
    __syncthreads();                                                            \
  } while (0)

  for (int t = 0; t < T_STEPS; t += 2) {
    RSTEP(t,     0,    8192, pfA);  // read buf0 (h_{t-1}), write buf1 (h_t)
    RSTEP(t + 1, 8192, 0,    pfB);  // read buf1, write buf0
  }
#undef RSTEP

  // ---- layer-0 epilogue: final h_2047 (buf0) -> h1 slots ----
  if (LAYER == 0 && w == 0) {
    char* hb = h1out + (size_t)2047 * 32768 + (size_t)bg * 8192 + rdoff;
#pragma unroll
    for (int c = 0; c < 8; ++c)
      *(u32x4v*)(hb + c * 1024) = *(const u32x4v*)(smem + c * 1024 + rdoff);
  }

  // ---- layer-1 epilogue FC: out[b][o] = h2[b][:] . fc_w[o][:] + fc_b[o]; h2 = buf0 ----
  if (LAYER == 1) {
    const int m  = tid >> 4;   // batch row within group
    const int og = tid & 15;   // output group of 8
    float a8[8];
#pragma unroll
    for (int oo = 0; oo < 8; ++oo) a8[oo] = fcb[og * 8 + oo];
    for (int c = 0; c < 8; ++c) {
#pragma unroll
      for (int qq = 0; qq < 4; ++qq) {
        const u32x4v hv = *(const u32x4v*)(smem + c * 1024 + (16 * qq + m) * 16);
        float hf[8];
        hf[0] = bf2f((ushort)(hv.x & 0xffff)); hf[1] = bf2f((ushort)(hv.x >> 16));
        hf[2] = bf2f((ushort)(hv.y & 0xffff)); hf[3] = bf2f((ushort)(hv.y >> 16));
        hf[4] = bf2f((ushort)(hv.z & 0xffff)); hf[5] = bf2f((ushort)(hv.z >> 16));
        hf[6] = bf2f((ushort)(hv.w & 0xffff)); hf[7] = bf2f((ushort)(hv.w >> 16));
        const int kb = 32 * c + 8 * qq;
#pragma unroll
        for (int oo = 0; oo < 8; ++oo) {
          const float* fw = fcw + (size_t)(og * 8 + oo) * 256 + kb;
          const float4 g0 = *(const float4*)(fw);
          const float4 g1 = *(const float4*)(fw + 4);
          a8[oo] += hf[0] * g0.x + hf[1] * g0.y + hf[2] * g0.z + hf[3] * g0.w
                  + hf[4] * g1.x + hf[5] * g1.y + hf[6] * g1.z + hf[7] * g1.w;
        }
      }
    }
#pragma unroll
    for (int oo = 0; oo < 8; ++oo)
      out[(16 * bg + m) * 128 + og * 8 + oo] = a8[oo];
  }
}

extern "C" void kernel_launch(void* const* d_in, const int* in_sizes, int n_in,
                              void* d_out, int out_size, void* d_ws, size_t ws_size,
                              hipStream_t stream) {
  (void)in_sizes; (void)n_in; (void)out_size;
  const float* x     = (const float*)d_in[0];
  const float* W_ih0 = (const float*)d_in[1];
  const float* W_hh0 = (const float*)d_in[2];
  const float* b_ih0 = (const float*)d_in[3];
  const float* b_hh0 = (const float*)d_in[4];
  const float* W_ih1 = (const float*)d_in[5];
  const float* W_hh1 = (const float*)d_in[6];
  const float* b_ih1 = (const float*)d_in[7];
  const float* b_hh1 = (const float*)d_in[8];
  const float* fcw   = (const float*)d_in[9];
  const float* fcb   = (const float*)d_in[10];

  const bool big = ws_size >= (size_t)201326592;  // 192 MiB
  if (big) {
    void* xp = d_ws;                               // 128 MiB fp32 fragment-linear
    char* h1 = (char*)d_ws + (size_t)134217728;    // 64 MiB h1 fragment-slot bytes
    proj_kernel<0, false><<<256, 256, 0, stream>>>(x, W_ih0, b_ih0, b_hh0, xp);
    recur_kernel<0, false><<<4, 256, 0, stream>>>(xp, W_hh0, h1, nullptr, nullptr, nullptr);
    proj_kernel<1, false><<<256, 256, 0, stream>>>(h1, W_ih1, b_ih1, b_hh1, xp);
    recur_kernel<1, false><<<4, 256, 0, stream>>>(xp, W_hh1, nullptr, fcw, fcb, (float*)d_out);
  } else {
    void* xp = d_ws;                               // 64 MiB bf16 fragment-linear
    char* h1 = (char*)d_ws + (size_t)67108864;     // 64 MiB h1 fragment-slot bytes
    proj_kernel<0, true><<<256, 256, 0, stream>>>(x, W_ih0, b_ih0, b_hh0, xp);
    recur_kernel<0, true><<<4, 256, 0, stream>>>(xp, W_hh0, h1, nullptr, nullptr, nullptr);
    proj_kernel<1, true><<<256, 256, 0, stream>>>(h1, W_ih1, b_ih1, b_hh1, xp);
    recur_kernel<1, true><<<4, 256, 0, stream>>>(xp, W_hh1, nullptr, fcw, fcb, (float*)d_out);
  }
}

// Round 7
// 4289.014 us; speedup vs baseline: 1.0761x; 1.0761x over previous
//
#include <hip/hip_runtime.h>
#include <hip/hip_bf16.h>
#include <stdint.h>

// Fused 2-layer ReLU RNN, B=64 T=2048 D=H=256 O=128.
// Round 7: flipped MFMA orientation (D = W·h, A=W B=h) so the C/D reg axis is
// n_out (next step's k): epilogue packs 4 consecutive k per acc via
// v_cvt_pk_bf16_f32 and writes ONE ds_write_b64 per tile (was 16 ds_write_b16
// + ~80 VALU RNE ops). W/h fragment loads and all slot formats unchanged;
// proj swapped identically (bias now per-element f32x4).
//
// Phases: proj0 -> recur0 (writes h1 as fragment-slot images) -> proj1 -> recur1+FC.
// h LDS layout (A-slot-linear): byte(m,k) = (k>>5)*1024 + ((k>>3)&3)*256 + m*16 + (k&7)*2
//   => reader lane L, k-block c does ONE ds_read_b128 at c*1024 + L*16;
//   => writer (flipped D): tile nt holds (n=64w+16nt+4q+j, batch=r), j=0..3
//      -> one b64 at (k0>>5)*1024 + ((k0>>3)&3)*256 + r*16 + (k0&7)*2, k0=64w+16nt+4q.
// Workspace tiers: ws >= 192MiB: fp32 xp (128M) + h1 slots (64M); else bf16 xp (64M) + h1 (64M).

typedef float    f32x4  __attribute__((ext_vector_type(4)));
typedef short    s16x8  __attribute__((ext_vector_type(8)));
typedef uint32_t u32x2  __attribute__((ext_vector_type(2)));
typedef uint32_t u32x4v __attribute__((ext_vector_type(4)));

#define T_STEPS 2048

template<bool C, class A, class B> struct cond_ { using type = A; };
template<class A, class B> struct cond_<false, A, B> { using type = B; };

static __device__ __forceinline__ ushort f2bf(float f) {  // RNE f32->bf16 (finite inputs)
  uint32_t u = __builtin_bit_cast(uint32_t, f);
  u += 0x7fffu + ((u >> 16) & 1u);
  return (ushort)(u >> 16);
}
static __device__ __forceinline__ float bf2f(ushort h) {
  return __builtin_bit_cast(float, (uint32_t)h << 16);
}
static __device__ __forceinline__ uint32_t packbf(float lo, float hi) {
  return (uint32_t)f2bf(lo) | ((uint32_t)f2bf(hi) << 16);
}
static __device__ __forceinline__ uint32_t cvtpk(float lo, float hi) {  // RNE, low=lo
  uint32_t d;
  asm("v_cvt_pk_bf16_f32 %0, %1, %2" : "=v"(d) : "v"(lo), "v"(hi));
  return d;
}
static __device__ __forceinline__ s16x8 pack8(float4 a, float4 b) {
  u32x4v u;
  u.x = packbf(a.x, a.y); u.y = packbf(a.z, a.w);
  u.z = packbf(b.x, b.y); u.w = packbf(b.z, b.w);
  return __builtin_bit_cast(s16x8, u);
}
struct hl2 { uint32_t hi, lo; };
static __device__ __forceinline__ hl2 split2(float a, float b) {  // hi/lo bf16 pair-pack
  const ushort ha = f2bf(a), hb = f2bf(b);
  const ushort la = f2bf(a - bf2f(ha)), lb = f2bf(b - bf2f(hb));
  hl2 r;
  r.hi = (uint32_t)ha | ((uint32_t)hb << 16);
  r.lo = (uint32_t)la | ((uint32_t)lb << 16);
  return r;
}
static __device__ __forceinline__ f32x4 expand16(u32x2 p) {  // 4 bf16 -> f32x4 (exact)
  f32x4 r;
  r.x = __builtin_bit_cast(float, p.x << 16);
  r.y = __builtin_bit_cast(float, p.x & 0xffff0000u);
  r.z = __builtin_bit_cast(float, p.y << 16);
  r.w = __builtin_bit_cast(float, p.y & 0xffff0000u);
  return r;
}
static __device__ __forceinline__ f32x4 acc_of(f32x4 v) { return v; }
static __device__ __forceinline__ f32x4 acc_of(u32x2 v) { return expand16(v); }

#define MFMA16(a, b, c) __builtin_amdgcn_mfma_f32_16x16x32_bf16((a), (b), (c), 0, 0, 0)

// ---------------- Projection GEMM:  xp[t][b][:] = in_row . W^T + (ba+bb) ----------------
// grid 256 x 256 threads. Wave w owns N-tiles 4w..4w+3.  FLIPPED: A=W_ih, B=x.
// Acc element j of tile nt = (j_out = 16*(4w+nt)+4q+j, batch = 16bg+r).
// MODE 0: inp = fp32 x [B][T][D].  MODE 1: inp = h1 fragment-slot bytes (from recur0).
// Output fragment-linear: frag idx = ((t*4+bg)*16 + nt)*64 + lane (f32x4 or u32x2 per tier).
template<int MODE, bool XP16>
__global__ __launch_bounds__(256, 2)
void proj_kernel(const void* __restrict__ inp, const float* __restrict__ W,
                 const float* __restrict__ ba, const float* __restrict__ bb,
                 void* __restrict__ xp)
{
  const int tid = threadIdx.x;
  const int w = tid >> 6, lane = tid & 63, q = lane >> 4, r = lane & 15;

  s16x8 wf[4][8];
  f32x4 bs4[4];
#pragma unroll
  for (int n = 0; n < 4; ++n) {
    const int j0 = 16 * (4 * w + n) + 4 * q;
    const float4 b0 = *(const float4*)(ba + j0);
    const float4 b1 = *(const float4*)(bb + j0);
    bs4[n].x = b0.x + b1.x; bs4[n].y = b0.y + b1.y;
    bs4[n].z = b0.z + b1.z; bs4[n].w = b0.w + b1.w;
    const int j = 16 * (4 * w + n) + r;
    const float* wr = W + (size_t)j * 256 + 8 * q;
#pragma unroll
    for (int c = 0; c < 8; ++c) {
      const float4 f0 = *(const float4*)(wr + 32 * c);
      const float4 f1 = *(const float4*)(wr + 32 * c + 4);
      wf[n][c] = pack8(f0, f1);
    }
  }

  const int t0 = blockIdx.x * 8;
  for (int tt = 0; tt < 8; ++tt) {
    const int t = t0 + tt;
    for (int bg = 0; bg < 4; ++bg) {
      s16x8 af[8];
      if (MODE == 1) {
        const unsigned char* hsl = (const unsigned char*)inp
            + (size_t)t * 32768 + (size_t)bg * 8192 + lane * 16;
#pragma unroll
        for (int c = 0; c < 8; ++c)
          af[c] = __builtin_bit_cast(s16x8, *(const u32x4v*)(hsl + c * 1024));
      } else {
        const float* arow = (const float*)inp + ((size_t)(16 * bg + r) * 2048 + t) * 256 + 8 * q;
#pragma unroll
        for (int c = 0; c < 8; ++c) {
          const float4 f0 = *(const float4*)(arow + 32 * c);
          const float4 f1 = *(const float4*)(arow + 32 * c + 4);
          af[c] = pack8(f0, f1);
        }
      }
      f32x4 a0 = bs4[0];
      f32x4 a1 = bs4[1];
      f32x4 a2 = bs4[2];
      f32x4 a3 = bs4[3];
#pragma unroll
      for (int c = 0; c < 8; ++c) {
        a0 = MFMA16(wf[0][c], af[c], a0);
        a1 = MFMA16(wf[1][c], af[c], a1);
        a2 = MFMA16(wf[2][c], af[c], a2);
        a3 = MFMA16(wf[3][c], af[c], a3);
      }
      const int ob = (t * 4 + bg) * 1024 + (4 * w) * 64 + lane;
      if constexpr (XP16) {
        u32x2* const xpo = (u32x2*)xp;
        u32x2 s0, s1, s2, s3;
        s0.x = packbf(a0.x, a0.y); s0.y = packbf(a0.z, a0.w);
        s1.x = packbf(a1.x, a1.y); s1.y = packbf(a1.z, a1.w);
        s2.x = packbf(a2.x, a2.y); s2.y = packbf(a2.z, a2.w);
        s3.x = packbf(a3.x, a3.y); s3.y = packbf(a3.z, a3.w);
        xpo[ob +   0] = s0;
        xpo[ob +  64] = s1;
        xpo[ob + 128] = s2;
        xpo[ob + 192] = s3;
      } else {
        f32x4* const xpo = (f32x4*)xp;
        xpo[ob +   0] = a0;
        xpo[ob +  64] = a1;
        xpo[ob + 128] = a2;
        xpo[ob + 192] = a3;
      }
    }
  }
}

// ---------------- Persistent recurrence ----------------
// 4 WGs (bg = blockIdx), 4 waves, 16 batches/WG. h_t = relu(xp_t + W_hh h_{t-1}).
// W_hh (hi+lo bf16) loaded straight from global into VGPRs (no LDS staging).
// LDS: two 8KB h buffers in A-slot-linear layout (see header).  FLIPPED MFMA.
template<int LAYER, bool XP16>
__global__ __launch_bounds__(256, 1)
void recur_kernel(const void* __restrict__ xp, const float* __restrict__ Whh,
                  char* __restrict__ h1out, const float* __restrict__ fcw,
                  const float* __restrict__ fcb, float* __restrict__ out)
{
  using XPT = typename cond_<XP16, u32x2, f32x4>::type;
  const int tid = threadIdx.x;
  const int w = tid >> 6, lane = tid & 63, q = lane >> 4, r = lane & 15;
  const int bg = blockIdx.x;

  __shared__ __align__(16) unsigned char smem[16384];

  // ---- W_hh hi/lo direct load: lane (q,r), tile n holds W[16*(4w+n)+r][8q+32c+{0..7}] ----
  s16x8 whi[4][8], wlo[4][8];
#pragma unroll
  for (int n = 0; n < 4; ++n) {
    const float* wr = Whh + (size_t)(16 * (4 * w + n) + r) * 256 + 8 * q;
#pragma unroll
    for (int c = 0; c < 8; ++c) {
      const float4 f0 = *(const float4*)(wr + 32 * c);
      const float4 f1 = *(const float4*)(wr + 32 * c + 4);
      const hl2 p0 = split2(f0.x, f0.y);
      const hl2 p1 = split2(f0.z, f0.w);
      const hl2 p2 = split2(f1.x, f1.y);
      const hl2 p3 = split2(f1.z, f1.w);
      u32x4v H, L;
      H.x = p0.hi; L.x = p0.lo;
      H.y = p1.hi; L.y = p1.lo;
      H.z = p2.hi; L.z = p2.lo;
      H.w = p3.hi; L.w = p3.lo;
      whi[n][c] = __builtin_bit_cast(s16x8, H);
      wlo[n][c] = __builtin_bit_cast(s16x8, L);
    }
  }

  // ---- zero both h buffers ----
  {
    uint32_t* z = (uint32_t*)smem;
#pragma unroll
    for (int i = 0; i < 16; ++i) z[tid + 256 * i] = 0u;
  }
  __syncthreads();

  const XPT* __restrict__ xpv = (const XPT*)xp;
  const int xpbase = bg * 1024 + (4 * w) * 64 + lane;

  XPT pfA[4], pfB[4];
#pragma unroll
  for (int n = 0; n < 4; ++n) {
    pfA[n] = xpv[xpbase + n * 64];
    pfB[n] = xpv[4096 + xpbase + n * 64];
  }

  // write bases (flipped D): tile nt holds (n = 64w+16nt+4q+j, batch m=r), j=0..3
  // -> k0 = 64w+16nt+4q; one b64 of 4 packed bf16 per tile.
  int wrb[4];
#pragma unroll
  for (int nt = 0; nt < 4; ++nt) {
    const int k0 = 64 * w + 16 * nt + 4 * q;
    wrb[nt] = (k0 >> 5) * 1024 + ((k0 >> 3) & 3) * 256 + r * 16 + (k0 & 7) * 2;
  }
  const int rdoff = lane * 16;

#define RSTEP(T_, RD_, WR_, PF_) do {                                           \
    u32x4v afr[8];                                                              \
    _Pragma("unroll")                                                           \
    for (int c = 0; c < 8; ++c)                                                 \
      afr[c] = *(const u32x4v*)(smem + (RD_) + c * 1024 + rdoff);               \
    if (LAYER == 0 && w == 0 && (T_) > 0) {                                     \
      char* hb = h1out + (size_t)((T_) - 1) * 32768 + (size_t)bg * 8192 + rdoff;\
      _Pragma("unroll")                                                         \
      for (int c = 0; c < 8; ++c) *(u32x4v*)(hb + c * 1024) = afr[c];           \
    }                                                                           \
    f32x4 ac0 = acc_of(PF_[0]), ac1 = acc_of(PF_[1]);                           \
    f32x4 ac2 = acc_of(PF_[2]), ac3 = acc_of(PF_[3]);                           \
    { int tp = (T_) + 2; if (tp > T_STEPS - 1) tp = T_STEPS - 1;                \
      const int xo = tp * 4096 + xpbase;                                        \
      PF_[0] = xpv[xo]; PF_[1] = xpv[xo + 64];                                  \
      PF_[2] = xpv[xo + 128]; PF_[3] = xpv[xo + 192]; }                         \
    _Pragma("unroll")                                                           \
    for (int c = 0; c < 8; ++c) {                                               \
      const s16x8 a = __builtin_bit_cast(s16x8, afr[c]);                        \
      ac0 = MFMA16(whi[0][c], a, ac0); ac1 = MFMA16(whi[1][c], a, ac1);         \
      ac2 = MFMA16(whi[2][c], a, ac2); ac3 = MFMA16(whi[3][c], a, ac3);         \
      ac0 = MFMA16(wlo[0][c], a, ac0); ac1 = MFMA16(wlo[1][c], a, ac1);         \
      ac2 = MFMA16(wlo[2][c], a, ac2); ac3 = MFMA16(wlo[3][c], a, ac3);         \
    }                                                                           \
    unsigned char* const wb = smem + (WR_);                                     \
    { u32x2 v0, v1, v2, v3;                                                     \
      v0.x = cvtpk(fmaxf(ac0.x, 0.f), fmaxf(ac0.y, 0.f));                       \
      v0.y = cvtpk(fmaxf(ac0.z, 0.f), fmaxf(ac0.w, 0.f));                       \
      v1.x = cvtpk(fmaxf(ac1.x, 0.f), fmaxf(ac1.y, 0.f));                       \
      v1.y = cvtpk(fmaxf(ac1.z, 0.f), fmaxf(ac1.w, 0.f));                       \
      v2.x = cvtpk(fmaxf(ac2.x, 0.f), fmaxf(ac2.y, 0.f));                       \
      v2.y = cvtpk(fmaxf(ac2.z, 0.f), fmaxf(ac2.w, 0.f));                       \
      v3.x = cvtpk(fmaxf(ac3.x, 0.f), fmaxf(ac3.y, 0.f));                       \
      v3.y = cvtpk(fmaxf(ac3.z, 0.f), fmaxf(ac3.w, 0.f));                       \
      *(u32x2*)(wb + wrb[0]) = v0;                                              \
      *(u32x2*)(wb + wrb[1]) = v1;                                              \
      *(u32x2*)(wb + wrb[2]) = v2;                                              \
      *(u32x2*)(wb + wrb[3]) = v3;                                              \
    }                                                                           \
    __syncthreads();                                                            \
  } while (0)

  for (int t = 0; t < T_STEPS; t += 2) {
    RSTEP(t,     0,    8192, pfA);  // read buf0 (h_{t-1}), write buf1 (h_t)
    RSTEP(t + 1, 8192, 0,    pfB);  // read buf1, write buf0
  }
#undef RSTEP

  // ---- layer-0 epilogue: final h_2047 (buf0) -> h1 slots ----
  if (LAYER == 0 && w == 0) {
    char* hb = h1out + (size_t)2047 * 32768 + (size_t)bg * 8192 + rdoff;
#pragma unroll
    for (int c = 0; c < 8; ++c)
      *(u32x4v*)(hb + c * 1024) = *(const u32x4v*)(smem + c * 1024 + rdoff);
  }

  // ---- layer-1 epilogue FC: out[b][o] = h2[b][:] . fc_w[o][:] + fc_b[o]; h2 = buf0 ----
  if (LAYER == 1) {
    const int m  = tid >> 4;   // batch row within group
    const int og = tid & 15;   // output group of 8
    float a8[8];
#pragma unroll
    for (int oo = 0; oo < 8; ++oo) a8[oo] = fcb[og * 8 + oo];
    for (int c = 0; c < 8; ++c) {
#pragma unroll
      for (int qq = 0; qq < 4; ++qq) {
        const u32x4v hv = *(const u32x4v*)(smem + c * 1024 + (16 * qq + m) * 16);
        float hf[8];
        hf[0] = bf2f((ushort)(hv.x & 0xffff)); hf[1] = bf2f((ushort)(hv.x >> 16));
        hf[2] = bf2f((ushort)(hv.y & 0xffff)); hf[3] = bf2f((ushort)(hv.y >> 16));
        hf[4] = bf2f((ushort)(hv.z & 0xffff)); hf[5] = bf2f((ushort)(hv.z >> 16));
        hf[6] = bf2f((ushort)(hv.w & 0xffff)); hf[7] = bf2f((ushort)(hv.w >> 16));
        const int kb = 32 * c + 8 * qq;
#pragma unroll
        for (int oo = 0; oo < 8; ++oo) {
          const float* fw = fcw + (size_t)(og * 8 + oo) * 256 + kb;
          const float4 g0 = *(const float4*)(fw);
          const float4 g1 = *(const float4*)(fw + 4);
          a8[oo] += hf[0] * g0.x + hf[1] * g0.y + hf[2] * g0.z + hf[3] * g0.w
                  + hf[4] * g1.x + hf[5] * g1.y + hf[6] * g1.z + hf[7] * g1.w;
        }
      }
    }
#pragma unroll
    for (int oo = 0; oo < 8; ++oo)
      out[(16 * bg + m) * 128 + og * 8 + oo] = a8[oo];
  }
}

extern "C" void kernel_launch(void* const* d_in, const int* in_sizes, int n_in,
                              void* d_out, int out_size, void* d_ws, size_t ws_size,
                              hipStream_t stream) {
  (void)in_sizes; (void)n_in; (void)out_size;
  const float* x     = (const float*)d_in[0];
  const float* W_ih0 = (const float*)d_in[1];
  const float* W_hh0 = (const float*)d_in[2];
  const float* b_ih0 = (const float*)d_in[3];
  const float* b_hh0 = (const float*)d_in[4];
  const float* W_ih1 = (const float*)d_in[5];
  const float* W_hh1 = (const float*)d_in[6];
  const float* b_ih1 = (const float*)d_in[7];
  const float* b_hh1 = (const float*)d_in[8];
  const float* fcw   = (const float*)d_in[9];
  const float* fcb   = (const float*)d_in[10];

  const bool big = ws_size >= (size_t)201326592;  // 192 MiB
  if (big) {
    void* xp = d_ws;                               // 128 MiB fp32 fragment-linear
    char* h1 = (char*)d_ws + (size_t)134217728;    // 64 MiB h1 fragment-slot bytes
    proj_kernel<0, false><<<256, 256, 0, stream>>>(x, W_ih0, b_ih0, b_hh0, xp);
    recur_kernel<0, false><<<4, 256, 0, stream>>>(xp, W_hh0, h1, nullptr, nullptr, nullptr);
    proj_kernel<1, false><<<256, 256, 0, stream>>>(h1, W_ih1, b_ih1, b_hh1, xp);
    recur_kernel<1, false><<<4, 256, 0, stream>>>(xp, W_hh1, nullptr, fcw, fcb, (float*)d_out);
  } else {
    void* xp = d_ws;                               // 64 MiB bf16 fragment-linear
    char* h1 = (char*)d_ws + (size_t)67108864;     // 64 MiB h1 fragment-slot bytes
    proj_kernel<0, true><<<256, 256, 0, stream>>>(x, W_ih0, b_ih0, b_hh0, xp);
    recur_kernel<0, true><<<4, 256, 0, stream>>>(xp, W_hh0, h1, nullptr, nullptr, nullptr);
    proj_kernel<1, true><<<256, 256, 0, stream>>>(h1, W_ih1, b_ih1, b_hh1, xp);
    recur_kernel<1, true><<<4, 256, 0, stream>>>(xp, W_hh1, nullptr, fcw, fcb, (float*)d_out);
  }
}